// Round 2
// baseline (483.326 us; speedup 1.0000x reference)
//
#include <hip/hip_runtime.h>
#include <hip/hip_bf16.h>

typedef __bf16 bf16x8 __attribute__((ext_vector_type(8)));
typedef float floatx4 __attribute__((ext_vector_type(4)));

// RNE fp32 -> bf16 (returns raw bits)
__device__ __forceinline__ unsigned f2bf(float f) {
    unsigned u = __float_as_uint(f);
    u += 0x7FFFu + ((u >> 16) & 1u);
    return u >> 16;
}

// async global->LDS, 16 bytes per lane; LDS base must be wave-uniform,
// HW writes lane l's 16B at base + l*16.
__device__ __forceinline__ void gl2lds(const void* g, void* l) {
    void* gnc = const_cast<void*>(g);
    __builtin_amdgcn_global_load_lds(
        (__attribute__((address_space(1))) void*)gnc,
        (__attribute__((address_space(3))) void*)l,
        16, 0, 0);
}

// -------- fused pre-pass: cast feat+centers fp32->bf16, fp32 row norms.
// Block = 256 threads = 2 rows x 128 threads; each thread: 8 floats (2x float4
// load), one 16B packed-bf16 store. Rows [0,M) -> feat/Ab/x2, [M,M+N) -> cent/Bb/c2.
__global__ __launch_bounds__(256) void cast_norm2(
    const float* __restrict__ feat, const float* __restrict__ cent,
    unsigned short* __restrict__ Ab, unsigned short* __restrict__ Bb,
    float* __restrict__ x2, float* __restrict__ c2, int M)
{
    const int tid  = threadIdx.x;
    const int half = tid >> 7;          // which row of the pair
    const int t    = tid & 127;         // position within row
    const int row  = blockIdx.x * 2 + half;

    const float* src;
    unsigned short* dst;
    float* nrm;
    if (row < M) {
        src = feat + (size_t)row * 1024;
        dst = Ab   + (size_t)row * 1024;
        nrm = x2 + row;
    } else {
        const int r = row - M;
        src = cent + (size_t)r * 1024;
        dst = Bb   + (size_t)r * 1024;
        nrm = c2 + r;
    }

    const float4 v0 = ((const float4*)src)[t * 2];
    const float4 v1 = ((const float4*)src)[t * 2 + 1];
    float s = v0.x * v0.x + v0.y * v0.y + v0.z * v0.z + v0.w * v0.w
            + v1.x * v1.x + v1.y * v1.y + v1.z * v1.z + v1.w * v1.w;

    uint4 o;
    o.x = f2bf(v0.x) | (f2bf(v0.y) << 16);
    o.y = f2bf(v0.z) | (f2bf(v0.w) << 16);
    o.z = f2bf(v1.x) | (f2bf(v1.y) << 16);
    o.w = f2bf(v1.z) | (f2bf(v1.w) << 16);
    ((uint4*)dst)[t] = o;

    // wave reduce (each wave belongs entirely to one row)
#pragma unroll
    for (int off = 32; off > 0; off >>= 1) s += __shfl_down(s, off);
    __shared__ float ws[4];
    if ((tid & 63) == 0) ws[tid >> 6] = s;
    __syncthreads();
    if (t == 0) *nrm = ws[half * 2] + ws[half * 2 + 1];
}

// -------- main kernel: bf16 MFMA GEMM (A·B^T) with fused distance epilogue
// 128x128 tile, BK=32, 256 threads (4 waves), wave -> 64x64, 4x4 x 16x16 MFMA.
__global__ __launch_bounds__(256) void dist_gemm(
    const unsigned short* __restrict__ A,   // [M][1024] bf16 (feat)
    const unsigned short* __restrict__ B,   // [N][1024] bf16 (centers)
    const float* __restrict__ x2,           // [M]
    const float* __restrict__ c2,           // [N]
    float* __restrict__ out,                // [M][N]
    int M, int N)
{
    constexpr int K = 1024;
    __shared__ unsigned short sA[128 * 32];   // row-major [128][32], no pad (global_load_lds)
    __shared__ unsigned short sB[128 * 32];

    const int tid  = threadIdx.x;
    const int wave = tid >> 6;
    const int lane = tid & 63;
    const int quad = lane >> 4;      // 0..3
    const int l16  = lane & 15;
    const int wm   = wave & 1;       // wave row (0..1)
    const int wn   = wave >> 1;      // wave col (0..1)

    // super-tile swizzle: 8x8 blocks per super-tile -> 4 MB (2MB A + 2MB B)
    // temporal working set instead of streaming all of B per A-band.
    const int gx = gridDim.x;                       // N/128
    const int lin = blockIdx.y * gx + blockIdx.x;   // dispatch order, x fastest
    const int tilesPerRow = gx >> 3;                // super-tiles per block-row
    const int super  = lin >> 6;                    // 64 blocks per super-tile
    const int within = lin & 63;
    const int bx = (super % tilesPerRow) * 8 + (within & 7);
    const int by = (super / tilesPerRow) * 8 + (within >> 3);

    const int blockRow = by * 128;
    const int blockCol = bx * 128;

    // staging map: chunk = 1024B = 16 rows; lane l -> row l/4, col (l&3)*8
    const int srow = lane >> 2;
    const int scol = (lane & 3) * 8;

    unsigned short* ldsA0 = sA + wave * 512;          // 512 ushort = 1024 B
    unsigned short* ldsA1 = sA + (wave + 4) * 512;
    unsigned short* ldsB0 = sB + wave * 512;
    unsigned short* ldsB1 = sB + (wave + 4) * 512;

    const unsigned short* gA0 = A + (size_t)(blockRow + wave * 16 + srow) * K + scol;
    const unsigned short* gA1 = A + (size_t)(blockRow + (wave + 4) * 16 + srow) * K + scol;
    const unsigned short* gB0 = B + (size_t)(blockCol + wave * 16 + srow) * K + scol;
    const unsigned short* gB1 = B + (size_t)(blockCol + (wave + 4) * 16 + srow) * K + scol;

    floatx4 acc[4][4];
#pragma unroll
    for (int i = 0; i < 4; i++)
#pragma unroll
        for (int j = 0; j < 4; j++) acc[i][j] = (floatx4){0.f, 0.f, 0.f, 0.f};

    // fragment read pointers: A[m][k]: m = l16 (tile-local), k = quad*8 + j
    const bf16x8* fragA[4];
    const bf16x8* fragB[4];
#pragma unroll
    for (int i = 0; i < 4; i++) {
        fragA[i] = (const bf16x8*)(sA + ((wm * 64 + i * 16 + l16) * 32 + quad * 8));
        fragB[i] = (const bf16x8*)(sB + ((wn * 64 + i * 16 + l16) * 32 + quad * 8));
    }

    for (int k0 = 0; k0 < K; k0 += 32) {
        __syncthreads();                      // prior compute done before LDS overwrite
        gl2lds(gA0 + k0, ldsA0);
        gl2lds(gA1 + k0, ldsA1);
        gl2lds(gB0 + k0, ldsB0);
        gl2lds(gB1 + k0, ldsB1);
        __syncthreads();                      // drains vmcnt(0) before barrier

        bf16x8 a[4], b[4];
#pragma unroll
        for (int i = 0; i < 4; i++) a[i] = *fragA[i];
#pragma unroll
        for (int j = 0; j < 4; j++) b[j] = *fragB[j];
#pragma unroll
        for (int i = 0; i < 4; i++)
#pragma unroll
            for (int j = 0; j < 4; j++)
                acc[i][j] = __builtin_amdgcn_mfma_f32_16x16x32_bf16(a[i], b[j], acc[i][j], 0, 0, 0);
    }

    // epilogue: dist = x2[row] + c2[col] - 2*xc
    // C/D layout: col = lane&15, row = quad*4 + reg
    // NT stores: out is write-once; bypass L2/L3 so A/B stay cache-resident.
    float c2v[4];
#pragma unroll
    for (int j = 0; j < 4; j++) c2v[j] = c2[blockCol + wn * 64 + j * 16 + l16];

#pragma unroll
    for (int i = 0; i < 4; i++) {
        const int rowb = blockRow + wm * 64 + i * 16 + quad * 4;
        float x2v[4];
#pragma unroll
        for (int r = 0; r < 4; r++) x2v[r] = x2[rowb + r];
#pragma unroll
        for (int j = 0; j < 4; j++) {
            const int col = blockCol + wn * 64 + j * 16 + l16;
            float* o = out + (size_t)rowb * N + col;
#pragma unroll
            for (int r = 0; r < 4; r++)
                __builtin_nontemporal_store(
                    fmaf(-2.0f, acc[i][j][r], x2v[r] + c2v[j]), o + (size_t)r * N);
        }
    }
}

// -------- fallback (only if ws_size too small): fp32 LDS-tiled direct distance
__global__ __launch_bounds__(256) void dist_fallback(
    const float* __restrict__ A, const float* __restrict__ B,
    float* __restrict__ out, int M, int N, int K)
{
    __shared__ float sA[64][17];
    __shared__ float sB[64][17];
    const int tid = threadIdx.x;
    const int tx = tid & 15;
    const int ty = tid >> 4;
    const int rowBase = blockIdx.y * 64;
    const int colBase = blockIdx.x * 64;
    float acc[4][4] = {};
    for (int k0 = 0; k0 < K; k0 += 16) {
        __syncthreads();
        {
            const int r = tid >> 2, c = (tid & 3) * 4;
            float4 va = *(const float4*)(A + (size_t)(rowBase + r) * K + k0 + c);
            sA[r][c] = va.x; sA[r][c + 1] = va.y; sA[r][c + 2] = va.z; sA[r][c + 3] = va.w;
            float4 vb = *(const float4*)(B + (size_t)(colBase + r) * K + k0 + c);
            sB[r][c] = vb.x; sB[r][c + 1] = vb.y; sB[r][c + 2] = vb.z; sB[r][c + 3] = vb.w;
        }
        __syncthreads();
#pragma unroll
        for (int kk = 0; kk < 16; kk++) {
            float ra[4], rb[4];
#pragma unroll
            for (int i = 0; i < 4; i++) ra[i] = sA[ty * 4 + i][kk];
#pragma unroll
            for (int j = 0; j < 4; j++) rb[j] = sB[tx * 4 + j][kk];
#pragma unroll
            for (int i = 0; i < 4; i++)
#pragma unroll
                for (int j = 0; j < 4; j++) {
                    float d = ra[i] - rb[j];
                    acc[i][j] = fmaf(d, d, acc[i][j]);
                }
        }
    }
#pragma unroll
    for (int i = 0; i < 4; i++)
#pragma unroll
        for (int j = 0; j < 4; j++)
            out[(size_t)(rowBase + ty * 4 + i) * N + (colBase + tx * 4 + j)] = acc[i][j];
}

extern "C" void kernel_launch(void* const* d_in, const int* in_sizes, int n_in,
                              void* d_out, int out_size, void* d_ws, size_t ws_size,
                              hipStream_t stream) {
    const float* feat = (const float*)d_in[0];
    const float* cent = (const float*)d_in[1];
    float* out = (float*)d_out;

    const int D = 1024;
    const int M = in_sizes[0] / D;   // 16384
    const int N = in_sizes[1] / D;   // 4096

    const size_t offA  = 0;
    const size_t offB  = offA + (size_t)M * D * sizeof(unsigned short);
    const size_t offX2 = offB + (size_t)N * D * sizeof(unsigned short);
    const size_t offC2 = offX2 + (size_t)M * sizeof(float);
    const size_t need  = offC2 + (size_t)N * sizeof(float);

    if (ws_size >= need && (M % 1024) == 0 && (N % 1024) == 0) {
        unsigned short* Ab = (unsigned short*)((char*)d_ws + offA);
        unsigned short* Bb = (unsigned short*)((char*)d_ws + offB);
        float* x2 = (float*)((char*)d_ws + offX2);
        float* c2 = (float*)((char*)d_ws + offC2);

        cast_norm2<<<(M + N) / 2, 256, 0, stream>>>(feat, cent, Ab, Bb, x2, c2, M);
        dist_gemm<<<dim3(N / 128, M / 128), 256, 0, stream>>>(Ab, Bb, x2, c2, out, M, N);
    } else {
        dist_fallback<<<dim3(N / 64, M / 64), 256, 0, stream>>>(feat, cent, out, M, N, D);
    }
}

// Round 3
// 470.171 us; speedup vs baseline: 1.0280x; 1.0280x over previous
//
#include <hip/hip_runtime.h>
#include <hip/hip_bf16.h>

typedef __bf16 bf16x8 __attribute__((ext_vector_type(8)));
typedef float floatx4 __attribute__((ext_vector_type(4)));

// RNE fp32 -> bf16 (returns raw bits)
__device__ __forceinline__ unsigned f2bf(float f) {
    unsigned u = __float_as_uint(f);
    u += 0x7FFFu + ((u >> 16) & 1u);
    return u >> 16;
}

// async global->LDS, 16 bytes per lane; LDS base must be wave-uniform,
// HW writes lane l's 16B at base + l*16.
__device__ __forceinline__ void gl2lds(const void* g, void* l) {
    void* gnc = const_cast<void*>(g);
    __builtin_amdgcn_global_load_lds(
        (__attribute__((address_space(1))) void*)gnc,
        (__attribute__((address_space(3))) void*)l,
        16, 0, 0);
}

// -------- fused pre-pass: cast feat+centers fp32->bf16, fp32 row norms.
// Block = 256 threads = 2 rows x 128 threads; each thread: 8 floats (2x float4
// load), one 16B packed-bf16 store. Rows [0,M) -> feat/Ab/x2, [M,M+N) -> cent/Bb/c2.
__global__ __launch_bounds__(256) void cast_norm2(
    const float* __restrict__ feat, const float* __restrict__ cent,
    unsigned short* __restrict__ Ab, unsigned short* __restrict__ Bb,
    float* __restrict__ x2, float* __restrict__ c2, int M)
{
    const int tid  = threadIdx.x;
    const int half = tid >> 7;          // which row of the pair
    const int t    = tid & 127;         // position within row
    const int row  = blockIdx.x * 2 + half;

    const float* src;
    unsigned short* dst;
    float* nrm;
    if (row < M) {
        src = feat + (size_t)row * 1024;
        dst = Ab   + (size_t)row * 1024;
        nrm = x2 + row;
    } else {
        const int r = row - M;
        src = cent + (size_t)r * 1024;
        dst = Bb   + (size_t)r * 1024;
        nrm = c2 + r;
    }

    const float4 v0 = ((const float4*)src)[t * 2];
    const float4 v1 = ((const float4*)src)[t * 2 + 1];
    float s = v0.x * v0.x + v0.y * v0.y + v0.z * v0.z + v0.w * v0.w
            + v1.x * v1.x + v1.y * v1.y + v1.z * v1.z + v1.w * v1.w;

    uint4 o;
    o.x = f2bf(v0.x) | (f2bf(v0.y) << 16);
    o.y = f2bf(v0.z) | (f2bf(v0.w) << 16);
    o.z = f2bf(v1.x) | (f2bf(v1.y) << 16);
    o.w = f2bf(v1.z) | (f2bf(v1.w) << 16);
    ((uint4*)dst)[t] = o;

    // wave reduce (each wave belongs entirely to one row)
#pragma unroll
    for (int off = 32; off > 0; off >>= 1) s += __shfl_down(s, off);
    __shared__ float ws[4];
    if ((tid & 63) == 0) ws[tid >> 6] = s;
    __syncthreads();
    if (t == 0) *nrm = ws[half * 2] + ws[half * 2 + 1];
}

// -------- main kernel: bf16 MFMA GEMM (A·B^T) with fused distance epilogue
// 128x128 tile, BK=32, 256 threads (4 waves), wave -> 64x64, 4x4 x 16x16 MFMA.
__global__ __launch_bounds__(256) void dist_gemm(
    const unsigned short* __restrict__ A,   // [M][1024] bf16 (feat)
    const unsigned short* __restrict__ B,   // [N][1024] bf16 (centers)
    const float* __restrict__ x2,           // [M]
    const float* __restrict__ c2,           // [N]
    float* __restrict__ out,                // [M][N]
    int M, int N)
{
    constexpr int K = 1024;
    __shared__ unsigned short sA[128 * 32];   // row-major [128][32], no pad (global_load_lds)
    __shared__ unsigned short sB[128 * 32];

    const int tid  = threadIdx.x;
    const int wave = tid >> 6;
    const int lane = tid & 63;
    const int quad = lane >> 4;      // 0..3
    const int l16  = lane & 15;
    const int wm   = wave & 1;       // wave row (0..1)
    const int wn   = wave >> 1;      // wave col (0..1)

    // XCD-aware mapping (heuristic: lin % 8 -> XCD, round-robin dispatch).
    // XCD x owns a column slab of gx/8 block-cols: its B slab (1 MB bf16)
    // stays L2-resident (reuse distance = colsPerXcd slots). All 8 XCDs
    // sweep A rows in lockstep -> A bands shared through L3 with tight
    // reuse distance, surviving the output-write L3 thrash.
    const int gx  = gridDim.x;                      // N/128, multiple of 8
    const int lin = blockIdx.y * gx + blockIdx.x;
    const int colsPerXcd = gx >> 3;
    const int xcd  = lin & 7;
    const int slot = lin >> 3;
    const int bx = xcd * colsPerXcd + (slot % colsPerXcd);
    const int by = slot / colsPerXcd;

    const int blockRow = by * 128;
    const int blockCol = bx * 128;

    // staging map: chunk = 1024B = 16 rows; lane l -> row l/4, col (l&3)*8
    const int srow = lane >> 2;
    const int scol = (lane & 3) * 8;

    unsigned short* ldsA0 = sA + wave * 512;          // 512 ushort = 1024 B
    unsigned short* ldsA1 = sA + (wave + 4) * 512;
    unsigned short* ldsB0 = sB + wave * 512;
    unsigned short* ldsB1 = sB + (wave + 4) * 512;

    const unsigned short* gA0 = A + (size_t)(blockRow + wave * 16 + srow) * K + scol;
    const unsigned short* gA1 = A + (size_t)(blockRow + (wave + 4) * 16 + srow) * K + scol;
    const unsigned short* gB0 = B + (size_t)(blockCol + wave * 16 + srow) * K + scol;
    const unsigned short* gB1 = B + (size_t)(blockCol + (wave + 4) * 16 + srow) * K + scol;

    floatx4 acc[4][4];
#pragma unroll
    for (int i = 0; i < 4; i++)
#pragma unroll
        for (int j = 0; j < 4; j++) acc[i][j] = (floatx4){0.f, 0.f, 0.f, 0.f};

    // fragment read pointers: A[m][k]: m = l16 (tile-local), k = quad*8 + j
    const bf16x8* fragA[4];
    const bf16x8* fragB[4];
#pragma unroll
    for (int i = 0; i < 4; i++) {
        fragA[i] = (const bf16x8*)(sA + ((wm * 64 + i * 16 + l16) * 32 + quad * 8));
        fragB[i] = (const bf16x8*)(sB + ((wn * 64 + i * 16 + l16) * 32 + quad * 8));
    }

    for (int k0 = 0; k0 < K; k0 += 32) {
        __syncthreads();                      // prior compute done before LDS overwrite
        gl2lds(gA0 + k0, ldsA0);
        gl2lds(gA1 + k0, ldsA1);
        gl2lds(gB0 + k0, ldsB0);
        gl2lds(gB1 + k0, ldsB1);
        __syncthreads();                      // drains vmcnt(0) before barrier

        bf16x8 a[4], b[4];
#pragma unroll
        for (int i = 0; i < 4; i++) a[i] = *fragA[i];
#pragma unroll
        for (int j = 0; j < 4; j++) b[j] = *fragB[j];
#pragma unroll
        for (int i = 0; i < 4; i++)
#pragma unroll
            for (int j = 0; j < 4; j++)
                acc[i][j] = __builtin_amdgcn_mfma_f32_16x16x32_bf16(a[i], b[j], acc[i][j], 0, 0, 0);
    }

    // epilogue: dist = x2[row] + c2[col] - 2*xc
    // C/D layout: col = lane&15, row = quad*4 + reg
    // Plain stores: L2 write-back merges the lane-scattered dwords into full
    // lines (round-1 WRITE_SIZE was exactly the 262 MB ideal; NT regressed it).
    float c2v[4];
#pragma unroll
    for (int j = 0; j < 4; j++) c2v[j] = c2[blockCol + wn * 64 + j * 16 + l16];

#pragma unroll
    for (int i = 0; i < 4; i++) {
        const int rowb = blockRow + wm * 64 + i * 16 + quad * 4;
        float x2v[4];
#pragma unroll
        for (int r = 0; r < 4; r++) x2v[r] = x2[rowb + r];
#pragma unroll
        for (int j = 0; j < 4; j++) {
            const int col = blockCol + wn * 64 + j * 16 + l16;
            float* o = out + (size_t)rowb * N + col;
#pragma unroll
            for (int r = 0; r < 4; r++)
                o[(size_t)r * N] = fmaf(-2.0f, acc[i][j][r], x2v[r] + c2v[j]);
        }
    }
}

// -------- fallback (only if ws_size too small): fp32 LDS-tiled direct distance
__global__ __launch_bounds__(256) void dist_fallback(
    const float* __restrict__ A, const float* __restrict__ B,
    float* __restrict__ out, int M, int N, int K)
{
    __shared__ float sA[64][17];
    __shared__ float sB[64][17];
    const int tid = threadIdx.x;
    const int tx = tid & 15;
    const int ty = tid >> 4;
    const int rowBase = blockIdx.y * 64;
    const int colBase = blockIdx.x * 64;
    float acc[4][4] = {};
    for (int k0 = 0; k0 < K; k0 += 16) {
        __syncthreads();
        {
            const int r = tid >> 2, c = (tid & 3) * 4;
            float4 va = *(const float4*)(A + (size_t)(rowBase + r) * K + k0 + c);
            sA[r][c] = va.x; sA[r][c + 1] = va.y; sA[r][c + 2] = va.z; sA[r][c + 3] = va.w;
            float4 vb = *(const float4*)(B + (size_t)(colBase + r) * K + k0 + c);
            sB[r][c] = vb.x; sB[r][c + 1] = vb.y; sB[r][c + 2] = vb.z; sB[r][c + 3] = vb.w;
        }
        __syncthreads();
#pragma unroll
        for (int kk = 0; kk < 16; kk++) {
            float ra[4], rb[4];
#pragma unroll
            for (int i = 0; i < 4; i++) ra[i] = sA[ty * 4 + i][kk];
#pragma unroll
            for (int j = 0; j < 4; j++) rb[j] = sB[tx * 4 + j][kk];
#pragma unroll
            for (int i = 0; i < 4; i++)
#pragma unroll
                for (int j = 0; j < 4; j++) {
                    float d = ra[i] - rb[j];
                    acc[i][j] = fmaf(d, d, acc[i][j]);
                }
        }
    }
#pragma unroll
    for (int i = 0; i < 4; i++)
#pragma unroll
        for (int j = 0; j < 4; j++)
            out[(size_t)(rowBase + ty * 4 + i) * N + (colBase + tx * 4 + j)] = acc[i][j];
}

extern "C" void kernel_launch(void* const* d_in, const int* in_sizes, int n_in,
                              void* d_out, int out_size, void* d_ws, size_t ws_size,
                              hipStream_t stream) {
    const float* feat = (const float*)d_in[0];
    const float* cent = (const float*)d_in[1];
    float* out = (float*)d_out;

    const int D = 1024;
    const int M = in_sizes[0] / D;   // 16384
    const int N = in_sizes[1] / D;   // 4096

    const size_t offA  = 0;
    const size_t offB  = offA + (size_t)M * D * sizeof(unsigned short);
    const size_t offX2 = offB + (size_t)N * D * sizeof(unsigned short);
    const size_t offC2 = offX2 + (size_t)M * sizeof(float);
    const size_t need  = offC2 + (size_t)N * sizeof(float);

    if (ws_size >= need && (M % 1024) == 0 && (N % 1024) == 0) {
        unsigned short* Ab = (unsigned short*)((char*)d_ws + offA);
        unsigned short* Bb = (unsigned short*)((char*)d_ws + offB);
        float* x2 = (float*)((char*)d_ws + offX2);
        float* c2 = (float*)((char*)d_ws + offC2);

        cast_norm2<<<(M + N) / 2, 256, 0, stream>>>(feat, cent, Ab, Bb, x2, c2, M);
        dist_gemm<<<dim3(N / 128, M / 128), 256, 0, stream>>>(Ab, Bb, x2, c2, out, M, N);
    } else {
        dist_fallback<<<dim3(N / 64, M / 64), 256, 0, stream>>>(feat, cent, out, M, N, D);
    }
}